// Round 3
// baseline (86.833 us; speedup 1.0000x reference)
//
#include <hip/hip_runtime.h>
#include <math.h>

// S4 Vandermonde kernel: K[h,l] = 2*Re( sum_n Ct[h,n] * exp(dtA[h,n])^l )
//   dt  = exp(log_dt)
//   A   = -exp(log_A_real) - i*A_imag
//   dtA = A*dt
//   Ct  = C * (exp(dtA)-1) / A        (complex)
//
// H=1024, NH=32, L=4096 (fixed).
//
// Round-3 structure: 4 blocks per h (grid 4096 > 2048 resident -> dynamic
// refill smooths the ~10x per-h work variance that made round-2 worst-CU
// bound). Block s of h owns interleaved l-chunks {s, s+4, s+8, s+12} of 256,
// so thread t's l-values are (s + 4k)*256 + t, k=0..3 (first-l <= 1023,
// recurrence stride 1024). Per active n: one exp + sin/cos startup (sin/cos
// fed REVOLUTIONS directly via v_sin_f32/v_cos_f32 on the pre-fracted phase,
// skipping the libm 2*pi round-trip), then up to kcap complex-multiply steps;
// kcap stops the recurrence once |z| < e^-40 (terms decay monotonically).

#define HH 1024
#define NH 32
#define LL 4096
#define BLOCK 256
#define CHUNK 4
#define SPLIT 4                 // blocks per h
#define STRIDE (BLOCK * SPLIT)  // 1024: l-stride between a thread's chunks

#define TWO_PI 6.28318530717958647692f
#define INV_TWO_PI 0.15915494309189533577f

__device__ __forceinline__ float sin_rev(float r) {  // r in [0,1) revolutions
    float d;
    asm("v_sin_f32 %0, %1" : "=v"(d) : "v"(r));
    return d;
}
__device__ __forceinline__ float cos_rev(float r) {
    float d;
    asm("v_cos_f32 %0, %1" : "=v"(d) : "v"(r));
    return d;
}

__global__ __launch_bounds__(BLOCK) void s4_vandermonde(
    const float* __restrict__ C,            // [H][NH][2]
    const float* __restrict__ log_dt,       // [H]
    const float* __restrict__ log_A_real,   // [H][NH]
    const float* __restrict__ A_imag,       // [H][NH]
    float* __restrict__ out)                // [H][LL]
{
    __shared__ float4 sA[NH];   // {ctr, cti, re, fm}
    __shared__ float4 sB[NH];   // {wr, wi, bitcast(kcap), unused}

    const int h = blockIdx.x >> 2;          // SPLIT == 4
    const int s = blockIdx.x & 3;
    const int t = threadIdx.x;

    if (t < NH) {
        const int n = t;
        const float dt  = __expf(log_dt[h]);
        const float Are = -__expf(log_A_real[h * NH + n]);
        const float Aim = -A_imag[h * NH + n];
        const float re = Are * dt;               // Re(dtA), negative
        const float im = Aim * dt;               // Im(dtA)
        // exp(dtA) - 1
        float s1, c1;
        __sincosf(im, &s1, &c1);
        const float er1 = __expf(re);
        const float X = er1 * c1 - 1.0f;
        const float Y = er1 * s1;
        // Ct = C * (exp(dtA)-1) / A, folded with the final factor of 2
        const float C0 = C[(h * NH + n) * 2 + 0];
        const float C1 = C[(h * NH + n) * 2 + 1];
        const float nr = C0 * X - C1 * Y;
        const float ni = C0 * Y + C1 * X;
        const float inv = 2.0f / (Are * Are + Aim * Aim);
        const float ctr = (nr * Are + ni * Aim) * inv;
        const float cti = (ni * Are - nr * Aim) * inv;
        const float fm = im * INV_TWO_PI;        // revolutions per unit l

        // wstep = exp(dtA * STRIDE) with double-precision phase reduction
        const float reS = re * (float)STRIDE;
        const float erS = (reS < -80.0f) ? 0.0f : __expf(reS);
        double revd = (double)fm * (double)STRIDE;
        revd -= floor(revd);
        float sS, cS;
        __sincosf((float)revd * TWO_PI, &sS, &cS);

        // kcap: k-steps before re*(STRIDE*k) < -40 (k=0 always live)
        const float kl = -40.0f / (re * (float)STRIDE);   // positive
        const int kcap = (kl >= (float)(CHUNK - 1)) ? CHUNK : ((int)kl + 1);

        sA[n] = make_float4(ctr, cti, re, fm);
        sB[n] = make_float4(erS * cS, erS * sS, __int_as_float(kcap), 0.0f);
    }
    __syncthreads();

    float acc[CHUNK];
#pragma unroll
    for (int k = 0; k < CHUNK; ++k) acc[k] = 0.0f;

    const float lf = (float)(s * BLOCK + t);     // thread's first l (<= 1023)

    for (int n = 0; n < NH; ++n) {
        const float4 A4 = sA[n];
        const float a = A4.z * lf;
        if (a < -40.0f) continue;                // term < 4e-18 at first l
        const float4 B4 = sB[n];
        const float er = __expf(a);
        float rev = A4.w * lf;
        rev -= floorf(rev);                      // [0,1) revolutions
        float zr = er * cos_rev(rev);
        float zi = er * sin_rev(rev);
        const int kcap = __float_as_int(B4.z);   // wave-uniform
#pragma unroll
        for (int k = 0; k < CHUNK; ++k) {
            if (k >= kcap) break;
            acc[k] += A4.x * zr - A4.y * zi;
            const float tr = zr * B4.x - zi * B4.y;
            zi = zr * B4.y + zi * B4.x;
            zr = tr;
        }
    }

    float* o = out + h * LL + s * BLOCK + t;
#pragma unroll
    for (int k = 0; k < CHUNK; ++k) o[k * STRIDE] = acc[k];
}

extern "C" void kernel_launch(void* const* d_in, const int* in_sizes, int n_in,
                              void* d_out, int out_size, void* d_ws, size_t ws_size,
                              hipStream_t stream) {
    const float* C          = (const float*)d_in[0];   // [1024][32][2]
    const float* log_dt     = (const float*)d_in[1];   // [1024]
    const float* log_A_real = (const float*)d_in[2];   // [1024][32]
    const float* A_imag     = (const float*)d_in[3];   // [1024][32]
    float* out              = (float*)d_out;           // [1024][4096]

    s4_vandermonde<<<dim3(HH * SPLIT), dim3(BLOCK), 0, stream>>>(
        C, log_dt, log_A_real, A_imag, out);
}

// Round 4
// 83.520 us; speedup vs baseline: 1.0397x; 1.0397x over previous
//
#include <hip/hip_runtime.h>
#include <math.h>

// S4 Vandermonde kernel: K[h,l] = 2*Re( sum_n Ct[h,n] * exp(dtA[h,n])^l )
//   dt  = exp(log_dt);  A = -exp(log_A_real) - i*A_imag;  dtA = A*dt
//   Ct  = C * (exp(dtA)-1) / A
// H=1024, NH=32, L=4096 (fixed).
//
// Round-4 structure (table + 2nd-order recurrence):
//  - 4 blocks per h; block s owns interleaved l-chunks {s, s+4, s+8, s+12} of
//    256: thread t's outputs are l = s*256 + t + k*1024, k=0..3.
//  - Per n, LDS tables: W16'[a] = 2*Ct*exp(dtA*(s*256+16a)), W1[b]=exp(dtA*b)
//    so V = W16'[t>>4] * W1[t&15] = 2*Ct*exp(dtA*lf) with NO per-thread
//    transcendentals (8x fewer exp/sincos than per-thread startup).
//  - Outputs u_k = Re(V * w^k), w = exp(dtA*1024), via the stable 2nd-order
//    real recurrence u_k = 2Re(w)*u_{k-1} - |w|^2*u_{k-2} (3 ops/output vs 8
//    for complex stepping; |w|<=1 so no error growth; underflow -> clean 0).
//  - Gate: skip n when re*lf < -16 (term < ~1e-7, threshold is 2.6e-2).

#define HH 1024
#define NH 32
#define LL 4096
#define BLOCK 256
#define SPLIT 4
#define STRIDE 1024

#define TWO_PI 6.28318530717958647692f
#define INV_TWO_PI 0.15915494309189533577f

__device__ __forceinline__ float sin_rev(float r) {  // r in [0,1) revolutions
    float d;
    asm("v_sin_f32 %0, %1" : "=v"(d) : "v"(r));
    return d;
}
__device__ __forceinline__ float cos_rev(float r) {
    float d;
    asm("v_cos_f32 %0, %1" : "=v"(d) : "v"(r));
    return d;
}

__global__ __launch_bounds__(BLOCK) void s4_vandermonde(
    const float* __restrict__ C,            // [H][NH][2]
    const float* __restrict__ log_dt,       // [H]
    const float* __restrict__ log_A_real,   // [H][NH]
    const float* __restrict__ A_imag,       // [H][NH]
    float* __restrict__ out)                // [H][LL]
{
    __shared__ float2 sW16[NH][16];  // 2*Ct*exp(dtA*(s*256+16a))
    __shared__ float2 sW1[NH][16];   // exp(dtA*b)
    __shared__ float4 sP[NH];        // {re, wSr, wSi, bS=|wS|^2}
    __shared__ float4 sAux[NH];      // {fm, ctr, cti, re}

    const int h = blockIdx.x >> 2;          // SPLIT == 4
    const int s = blockIdx.x & 3;
    const int t = threadIdx.x;

    // ---- phase 0: per-n scalars (lanes 0..31) ----
    if (t < NH) {
        const int n = t;
        const float dt  = __expf(log_dt[h]);
        const float Are = -__expf(log_A_real[h * NH + n]);
        const float Aim = -A_imag[h * NH + n];
        const float re = Are * dt;               // Re(dtA), negative
        const float im = Aim * dt;               // Im(dtA)
        float s1, c1;
        __sincosf(im, &s1, &c1);
        const float er1 = __expf(re);
        const float X = er1 * c1 - 1.0f;
        const float Y = er1 * s1;
        const float C0 = C[(h * NH + n) * 2 + 0];
        const float C1 = C[(h * NH + n) * 2 + 1];
        const float nr = C0 * X - C1 * Y;
        const float ni = C0 * Y + C1 * X;
        const float inv = 2.0f / (Are * Are + Aim * Aim);  // folds final x2
        const float ctr = (nr * Are + ni * Aim) * inv;
        const float cti = (ni * Are - nr * Aim) * inv;
        const float fm = im * INV_TWO_PI;        // revolutions per unit l

        // w = exp(dtA * 1024), double-precision phase reduction
        const float erS = __expf(re * 1024.0f); // underflows cleanly to 0
        double revd = (double)im * (double)INV_TWO_PI * 1024.0;
        revd -= floor(revd);
        float sS, cS;
        __sincosf((float)revd * TWO_PI, &sS, &cS);

        sP[n]   = make_float4(re, erS * cS, erS * sS, erS * erS);
        sAux[n] = make_float4(fm, ctr, cti, re);
    }
    __syncthreads();

    // ---- phase 1: build tables (all 256 threads; 4 entries each) ----
    {
        const int n = t >> 3;
        const int j = t & 7;
        const float4 aux = sAux[n];
        const float fm = aux.x, ctr = aux.y, cti = aux.z, re = aux.w;
#pragma unroll
        for (int q = 0; q < 2; ++q) {
            const int e = j + q * 8;
            // W1[e] = exp(dtA * e), e in [0,16)
            {
                const float er = __expf(re * (float)e);
                float rev = fm * (float)e;
                rev -= floorf(rev);
                sW1[n][e] = make_float2(er * cos_rev(rev), er * sin_rev(rev));
            }
            // W16'[e] = 2*Ct * exp(dtA * (s*256 + 16e)), m <= 1008
            {
                const float m = (float)(s * 256 + 16 * e);
                const float er = __expf(re * m);
                float rev = fm * m;
                rev -= floorf(rev);
                const float br = er * cos_rev(rev);
                const float bi = er * sin_rev(rev);
                sW16[n][e] = make_float2(ctr * br - cti * bi,
                                         ctr * bi + cti * br);
            }
        }
    }
    __syncthreads();

    // ---- main loop ----
    float acc0 = 0.0f, acc1 = 0.0f, acc2 = 0.0f, acc3 = 0.0f;
    const float lf = (float)(s * BLOCK + t);     // first l (<= 1023)
    const int hi = t >> 4, lo = t & 15;

    for (int n = 0; n < NH; ++n) {
        const float4 P = sP[n];                  // broadcast read
        if (P.x * lf < -16.0f) continue;         // term < ~1e-7, decays only
        const float2 a2 = sW16[n][hi];
        const float2 b2 = sW1[n][lo];
        const float vr = a2.x * b2.x - a2.y * b2.y;   // V = 2*Ct*exp(dtA*lf)
        const float vi = a2.x * b2.y + a2.y * b2.x;
        acc0 += vr;                              // u0 = Re(V)
        const float u1 = vr * P.y - vi * P.z;    // u1 = Re(V*w)
        acc1 += u1;
        const float aS = P.y + P.y;              // 2*Re(w)
        const float u2 = aS * u1 - P.w * vr;     // u2 = aS*u1 - |w|^2*u0
        acc2 += u2;
        const float u3 = aS * u2 - P.w * u1;
        acc3 += u3;
    }

    float* o = out + h * LL + s * BLOCK + t;
    o[0]          = acc0;
    o[STRIDE]     = acc1;
    o[2 * STRIDE] = acc2;
    o[3 * STRIDE] = acc3;
}

extern "C" void kernel_launch(void* const* d_in, const int* in_sizes, int n_in,
                              void* d_out, int out_size, void* d_ws, size_t ws_size,
                              hipStream_t stream) {
    const float* C          = (const float*)d_in[0];   // [1024][32][2]
    const float* log_dt     = (const float*)d_in[1];   // [1024]
    const float* log_A_real = (const float*)d_in[2];   // [1024][32]
    const float* A_imag     = (const float*)d_in[3];   // [1024][32]
    float* out              = (float*)d_out;           // [1024][4096]

    s4_vandermonde<<<dim3(HH * SPLIT), dim3(BLOCK), 0, stream>>>(
        C, log_dt, log_A_real, A_imag, out);
}